// Round 1
// baseline (137.709 us; speedup 1.0000x reference)
//
#include <hip/hip_runtime.h>

// VQ-VAE VectorQuantizer forward, MI355X (gfx950), fp32.
// N=32768 points x D=64 dims, K=1024 codes.
// Out: [0]=loss, [1..QE]=quantized [B,D,H,W], [+..]=indices [B,H*W] as f32.
//
// R5: occupancy attack. R4 was latency-bound (VALUBusy 43%, 2 waves/SIMD,
// 1 block/CU due to 105KB LDS). Same grid(256)/LDS layout/chunking, but
// 1024 threads -> 16 waves/CU = 4 waves/SIMD. Wave re-tiled as 32pt x 64code
// (per-thread 4x8, acc=32 VGPR << 128 cap): x-reads become pure same-address
// broadcast (free), e-reads 8 distinct contiguous addrs with 2-way aliasing
// (free, m136). Argmin = in-wave butterfly over 8 code-lanes + 4-way LDS
// combine across the 4 code-block waves (global min, tie -> lower idx --
// identical semantics to R4 since every u is bit-identical).
// Loss epilogue runs on t<512 with R4's EXACT per-thread partition and
// redbuf[8] summation order -> loss bits unchanged. absmax must stay 0.

constexpr int D_   = 64;
constexpr int HW   = 1024;     // H*W
constexpr int K_   = 1024;
constexpr int PTS  = 128;      // points per block
constexpr int SP   = 132;      // xT row stride (floats)
constexpr int SEC  = 260;      // eT row stride (floats)
constexpr int CK   = 256;      // codes per chunk
constexpr int QE   = 2097152;
constexpr int IDX_OFF = 1 + QE;

__global__ __launch_bounds__(1024, 4) void vq_main_kernel(
    const float* __restrict__ in, const float* __restrict__ emb,
    float* __restrict__ out, float* __restrict__ loss_acc,
    unsigned* __restrict__ cnt) {
  __shared__ float xT[D_ * SP];      // [d][p] 33.8 KB; later holds ST values
  __shared__ float eTs[D_ * SEC];    // [d][k_local] 66.6 KB
  __shared__ float e2s[K_];          // 4 KB
  __shared__ float x2s[PTS];
  __shared__ int   idx_sel[PTS];
  __shared__ float redbuf[8];
  __shared__ float vred[4][PTS];     // per-code-block partial min values
  __shared__ int   ired[4][PTS];     // per-code-block partial min indices

  const int t    = threadIdx.x;
  const int lane = t & 63;
  const int w    = t >> 6;           // wave 0..15
  const int pb   = w >> 2;           // point block: 32 points (4 blocks)
  const int kb   = w & 3;            // code block: 64 codes  (4 blocks)
  const int lpg  = lane & 7;         // in-wave point group: 4 points
  const int lkg  = lane >> 3;        // in-wave code group: 8 codes
  const int p0   = pb * 32 + lpg * 4;       // first of this thread's 4 points
  const int blk = blockIdx.x;
  const int b   = blk >> 3;          // 8 blocks per image
  const int hw0 = (blk & 7) * PTS;
  const float* inb = in + b * (D_ * HW) + hw0;

  // staging role: thread handles chunk-local code kl, dim-quarter h
  const int kl = t & 255;            // 0..255 (64 consecutive per wave)
  const int h  = t >> 8;             // dims h*16 .. h*16+15 (wave-uniform)

  // ---- stage x tile -> xT[d][p] (coalesced float4) ----
#pragma unroll
  for (int i = 0; i < 2; ++i) {
    int fi = t + i * 1024;                // 0..2047
    int d  = fi >> 5, p4 = fi & 31;
    *(float4*)(&xT[d * SP + p4 * 4]) = *(const float4*)(inb + d * HW + p4 * 4);
  }

  // ---- e2s: 1 code/thread, body identical to R4 (rounding!) ----
  {
    const float4* e4 = (const float4*)(emb + t * 64);
    float s = 0.f;
#pragma unroll
    for (int q = 0; q < 16; ++q) {
      float4 v = e4[q];
      s += v.x * v.x; s += v.y * v.y; s += v.z * v.z; s += v.w * v.w;
    }
    e2s[t] = s;
  }

  // ---- prefetch + stage chunk 0 ----
  // write bank = (4d+kl)%32 = (16r+4j+kl)%32; kl spans 64 consecutive per
  // wave, h wave-uniform -> 2 lanes/bank, distinct addrs: 2-way = free.
  float4 pf[4];
  {
    const float4* g = (const float4*)(emb + kl * 64 + h * 16);
#pragma unroll
    for (int r = 0; r < 4; ++r) pf[r] = g[r];
#pragma unroll
    for (int r = 0; r < 4; ++r) {
      int d = h * 16 + r * 4;
      eTs[(d + 0) * SEC + kl] = pf[r].x;
      eTs[(d + 1) * SEC + kl] = pf[r].y;
      eTs[(d + 2) * SEC + kl] = pf[r].z;
      eTs[(d + 3) * SEC + kl] = pf[r].w;
    }
  }
  __syncthreads();

  // ---- x2[p] (sequential d fmaf chain — identical to R4) ----
  if (t < PTS) {
    float s = 0.f;
#pragma unroll 8
    for (int d = 0; d < D_; ++d) { float xv = xT[d * SP + t]; s = fmaf(xv, xv, s); }
    x2s[t] = s;
  }
  __syncthreads();

  float x2r[4];
  {
    float4 xa = *(const float4*)&x2s[p0];
    x2r[0] = xa.x; x2r[1] = xa.y; x2r[2] = xa.z; x2r[3] = xa.w;
  }

  float minv[4]; int mini[4];
#pragma unroll
  for (int i = 0; i < 4; ++i) { minv[i] = 3.4e38f; mini[i] = 0; }

  // ---- K loop: 4 chunks of 256 codes ----
#pragma unroll 1
  for (int c = 0; c < 4; ++c) {
    // prefetch next chunk into regs (hidden under compute below)
    if (c < 3) {
      const float4* g = (const float4*)(emb + ((c + 1) * CK + kl) * 64 + h * 16);
#pragma unroll
      for (int r = 0; r < 4; ++r) pf[r] = g[r];
    }

    float acc[4][8];
#pragma unroll
    for (int i = 0; i < 4; ++i)
#pragma unroll
      for (int j = 0; j < 8; ++j) acc[i][j] = 0.f;

    const float* xp = &xT[p0];                 // single addr/wave: broadcast
    const float* ep = &eTs[kb * 64 + lkg * 8]; // 8 distinct addrs, 2-way bank
#pragma unroll 2
    for (int d = 0; d < D_; ++d) {
      float4 xa = *(const float4*)(xp);
      float4 e0 = *(const float4*)(ep);
      float4 e1 = *(const float4*)(ep + 4);
      xp += SP; ep += SEC;
      float xf[4] = {xa.x, xa.y, xa.z, xa.w};
      float ef[8] = {e0.x, e0.y, e0.z, e0.w, e1.x, e1.y, e1.z, e1.w};
#pragma unroll
      for (int i = 0; i < 4; ++i)
#pragma unroll
        for (int j = 0; j < 8; ++j)
          acc[i][j] = fmaf(xf[i], ef[j], acc[i][j]);
    }

    // fold: u = fl(fl(x2 - 2*dot) + e2) — identical expression/order to R4
    float e2f[8];
    {
      const float4* p4 = (const float4*)&e2s[c * CK + kb * 64 + lkg * 8];
      float4 v0 = p4[0], v1 = p4[1];
      e2f[0] = v0.x; e2f[1] = v0.y; e2f[2] = v0.z; e2f[3] = v0.w;
      e2f[4] = v1.x; e2f[5] = v1.y; e2f[6] = v1.z; e2f[7] = v1.w;
    }
#pragma unroll
    for (int j = 0; j < 8; ++j) {
      int cg = c * CK + kb * 64 + lkg * 8 + j;   // ascending within thread
      float e2v = e2f[j];
#pragma unroll
      for (int i = 0; i < 4; ++i) {
        float u = fmaf(-2.f, acc[i][j], x2r[i]) + e2v;
        if (u < minv[i]) { minv[i] = u; mini[i] = cg; }
      }
    }

    if (c < 3) {
      __syncthreads();   // all waves done reading eTs chunk c
#pragma unroll
      for (int r = 0; r < 4; ++r) {
        int d = h * 16 + r * 4;
        eTs[(d + 0) * SEC + kl] = pf[r].x;
        eTs[(d + 1) * SEC + kl] = pf[r].y;
        eTs[(d + 2) * SEC + kl] = pf[r].z;
        eTs[(d + 3) * SEC + kl] = pf[r].w;
      }
      __syncthreads();
    }
  }

  // ---- argmin stage 1: butterfly over the 8 lkg lanes (bits 3..5) ----
#pragma unroll
  for (int i = 0; i < 4; ++i) {
    float v = minv[i]; int ix = mini[i];
#pragma unroll
    for (int off = 8; off < 64; off <<= 1) {
      float vo = __shfl_xor(v, off);
      int   io = __shfl_xor(ix, off);
      if (vo < v || (vo == v && io < ix)) { v = vo; ix = io; }  // tie -> lower
    }
    if (lkg == 0) { vred[kb][p0 + i] = v; ired[kb][p0 + i] = ix; }
  }
  __syncthreads();

  // ---- argmin stage 2: combine the 4 code-block waves ----
  if (t < PTS) {
    float bv = vred[0][t]; int bix = ired[0][t];
#pragma unroll
    for (int q = 1; q < 4; ++q) {
      float v = vred[q][t]; int ix = ired[q][t];
      if (v < bv || (v == bv && ix < bix)) { bv = v; bix = ix; }
    }
    idx_sel[t] = bix;
    out[IDX_OFF + blk * PTS + t] = (float)bix;
  }
  __syncthreads();

  // ---- gather codes, loss partial, overwrite xT with x + (q - x) ----
  // t<512 only, with R4's EXACT per-thread partition -> loss bits identical.
  float lp = 0.f;
  if (t < 512) {
#pragma unroll
    for (int i = 0; i < 4; ++i) {
      int fi = t + i * 512;               // 0..2047
      int p = fi & 127, qd = fi >> 7;     // p contiguous per wave
      int cidx = idx_sel[p];
      float4 q = *(const float4*)(emb + cidx * 64 + qd * 4);
      float xv0 = xT[(qd * 4 + 0) * SP + p];
      float xv1 = xT[(qd * 4 + 1) * SP + p];
      float xv2 = xT[(qd * 4 + 2) * SP + p];
      float xv3 = xT[(qd * 4 + 3) * SP + p];
      float d0 = q.x - xv0, d1 = q.y - xv1, d2 = q.z - xv2, d3 = q.w - xv3;
      lp = fmaf(d0, d0, lp); lp = fmaf(d1, d1, lp);
      lp = fmaf(d2, d2, lp); lp = fmaf(d3, d3, lp);
      xT[(qd * 4 + 0) * SP + p] = xv0 + d0;
      xT[(qd * 4 + 1) * SP + p] = xv1 + d1;
      xT[(qd * 4 + 2) * SP + p] = xv2 + d2;
      xT[(qd * 4 + 3) * SP + p] = xv3 + d3;
    }

    // loss: wave -> block partials in R4's exact order (waves 0..7)
#pragma unroll
    for (int off = 1; off < 64; off <<= 1) lp += __shfl_xor(lp, off);
    if ((t & 63) == 0) redbuf[t >> 6] = lp;
  }
  __syncthreads();   // also orders xT rewrites before the stores below
  if (t == 0) {
    float part = 0.f;
#pragma unroll
    for (int wv = 0; wv < 8; ++wv) part += redbuf[wv];
    atomicAdd(loss_acc, part);
    __threadfence();
    unsigned old = atomicAdd(cnt, 1u);
    if (old == 255u) {
      __threadfence();
      float total = atomicAdd(loss_acc, 0.0f);  // coherent read-back
      float m = total * (1.0f / 2097152.0f);
      out[0] = m + 0.25f * m;                   // ref op order
    }
  }

  // quantized output [B,D,H,W]: scalar coalesced stores (out+1 is 4B-aligned)
  float* outq = out + 1 + b * (D_ * HW) + hw0;
#pragma unroll
  for (int i = 0; i < 8; ++i) {
    int oi = t + i * 1024;                // 0..8191
    int d = oi >> 7, p = oi & 127;
    outq[d * HW + p] = xT[d * SP + p];
  }
}

extern "C" void kernel_launch(void* const* d_in, const int* in_sizes, int n_in,
                              void* d_out, int out_size, void* d_ws, size_t ws_size,
                              hipStream_t stream) {
  const float* in  = (const float*)d_in[0];
  const float* emb = (const float*)d_in[1];
  float* out = (float*)d_out;
  float* loss_acc = (float*)d_ws;                 // ws[0]
  unsigned* cnt   = (unsigned*)d_ws + 4;          // ws[4]

  hipMemsetAsync(d_ws, 0, 64, stream);            // zero accumulator + counter
  vq_main_kernel<<<256, 1024, 0, stream>>>(in, emb, out, loss_acc, cnt);
}